// Round 1
// baseline (550.124 us; speedup 1.0000x reference)
//
#include <hip/hip_runtime.h>

#define NT      2000
#define BATCH   4096
#define NODES   64
#define TBL_N   16384

__device__ __forceinline__ float sigm_stable(float x) {
    // stable logistic; only transition region matters for accuracy
    float e = __expf(-fabsf(x));
    float s = 1.0f / (1.0f + e);
    return x >= 0.0f ? s : 1.0f - s;
}

// ---------------- kernel 1: build rho(j) lookup table ----------------
__global__ __launch_bounds__(256) void build_table(
    const float* __restrict__ W1, const float* __restrict__ b1,
    const float* __restrict__ W2, const float* __restrict__ b2,
    const float* __restrict__ W3, const float* __restrict__ b3,
    float* __restrict__ tbl) {
    __shared__ float sW2[NODES * NODES];
    __shared__ float sW1[NODES], sB1[NODES], sB2[NODES], sW3[NODES];
    __shared__ float sB3;
    for (int i = threadIdx.x; i < NODES * NODES; i += 256) sW2[i] = W2[i];
    if (threadIdx.x < NODES) {
        sW1[threadIdx.x] = W1[threadIdx.x];
        sB1[threadIdx.x] = b1[threadIdx.x];
        sB2[threadIdx.x] = b2[threadIdx.x];
        sW3[threadIdx.x] = W3[threadIdx.x];
    }
    if (threadIdx.x == 0) sB3 = b3[0];
    __syncthreads();

    int idx = blockIdx.x * 256 + threadIdx.x;
    if (idx >= TBL_N) return;
    const float h = 3.6f / (float)TBL_N;
    float j = h * (float)idx;

    float h1[NODES];
#pragma unroll
    for (int k = 0; k < NODES; ++k)
        h1[k] = fmaxf(fmaf(j, sW1[k], sB1[k]), 0.0f);

    float rho = sB3;
    for (int nt = 0; nt < NODES; nt += 8) {
        float acc[8];
#pragma unroll
        for (int q = 0; q < 8; ++q) acc[q] = sB2[nt + q];
#pragma unroll
        for (int k = 0; k < NODES; ++k) {
            float a = h1[k];
#pragma unroll
            for (int q = 0; q < 8; ++q)
                acc[q] = fmaf(a, sW2[k * NODES + nt + q], acc[q]);
        }
#pragma unroll
        for (int q = 0; q < 8; ++q)
            rho = fmaf(fmaxf(acc[q], 0.0f), sW3[nt + q], rho);
    }
    tbl[idx] = rho;
}

// ---------------- kernel 2: per-lane sequential simulation ----------------
__global__ __launch_bounds__(64) void simulate(
    const float* __restrict__ Cv, const float* __restrict__ K,
    const float* __restrict__ jmin, const float* __restrict__ tbl,
    float* __restrict__ out) {
    __shared__ float stbl[TBL_N];
    // cooperative vectorized copy of the table into LDS
    {
        int t4 = threadIdx.x * 4;
        for (int i = t4; i < TBL_N; i += 64 * 4)
            *reinterpret_cast<float4*>(&stbl[i]) =
                *reinterpret_cast<const float4*>(&tbl[i]);
    }
    __syncthreads();

    const int b = blockIdx.x * 64 + threadIdx.x;
    const float cv = Cv[b];
    const float kk = K[b];
    const float jm = jmin[b];

    // beta = 0.14/(0.14*50+1) = 0.0175 ; (81/(128*beta))^(1/3) = 3.3068337
    const float Qmin = 3.3068337f * powf(kk, 1.33333337f);

    const float SIGMA_ = 0.14f, L_ = 1.0f, DT_ = 0.1f, RF0 = 50.0f, SCALE_ = 1e9f;
    const float invh = (float)TBL_N / 3.6f;

    float* __restrict__ tout = out;
    float* __restrict__ rout = out + (size_t)BATCH * NT;
    float* __restrict__ cout_ = out + 2 * (size_t)BATCH * NT;
    float* __restrict__ timo = out + 3 * (size_t)BATCH * NT;
    const size_t base = (size_t)b * NT;

    tout[base] = 0.0f;
    rout[base] = RF0;
    cout_[base] = 1e-3f;
    timo[base] = 0.0f;

    float res = RF0, thk = 0.0f, Q = 0.0f;

    for (int i = 0; i < NT - 1; ++i) {
        float BC = DT_ * (float)(i + 1);              // VR = 1
        float jcur = (SIGMA_ * BC) / fmaf(SIGMA_, res, L_);
        float Qn = fmaf(jcur, DT_, Q);

        // table lerp for rho(jcur)
        float x = jcur * invh;
        int i0 = (int)x;
        if (i0 > TBL_N - 2) i0 = TBL_N - 2;
        float fr = x - (float)i0;
        float t0 = stbl[i0];
        float t1 = stbl[i0 + 1];
        float rho = fmaf(fr, t1 - t0, t0);

        float d1 = jcur - jm;
        float inc_t = cv * d1 * DT_;
        float inc_r = rho * d1 * DT_ * cv;

        // _limit(thk + inc_t, 0)
        float thk_c = thk + inc_t;
        float thk_l = fmaf(thk_c, sigm_stable(SCALE_ * thk_c), 0.0f);
        // _limit(res + inc_r, RF0)
        float res_c = res + inc_r;
        float dr = res_c - RF0;
        float res_l = fmaf(dr, sigm_stable(SCALE_ * dr), RF0);

        // _tradeoff(.., coord=Qn, lim=Qmin)
        float g = sigm_stable(SCALE_ * (Qn - Qmin));
        thk = fmaf(thk_l - thk, g, thk);
        res = fmaf(res_l - res, g, res);
        Q = Qn;

        size_t o = base + (size_t)(i + 1);
        tout[o] = thk;
        rout[o] = res;
        cout_[o] = jcur;
        timo[o] = BC;
    }
}

extern "C" void kernel_launch(void* const* d_in, const int* in_sizes, int n_in,
                              void* d_out, int out_size, void* d_ws, size_t ws_size,
                              hipStream_t stream) {
    const float* Cv   = (const float*)d_in[0];
    const float* K    = (const float*)d_in[1];
    const float* jmin = (const float*)d_in[2];
    const float* W1   = (const float*)d_in[3];
    const float* b1   = (const float*)d_in[4];
    const float* W2   = (const float*)d_in[5];
    const float* b2   = (const float*)d_in[6];
    const float* W3   = (const float*)d_in[7];
    const float* b3   = (const float*)d_in[8];
    float* out = (float*)d_out;
    float* tbl = (float*)d_ws;   // TBL_N floats = 64 KB of scratch

    build_table<<<TBL_N / 256, 256, 0, stream>>>(W1, b1, W2, b2, W3, b3, tbl);
    simulate<<<BATCH / 64, 64, 0, stream>>>(Cv, K, jmin, tbl, out);
}

// Round 2
// 246.146 us; speedup vs baseline: 2.2349x; 2.2349x over previous
//
#include <hip/hip_runtime.h>

#define NT      2000
#define BATCH   4096
#define NODES   64
#define TBL_N   8192
#define JMAX    3.6f

// ---------------- MLP evaluation helper (build phase only) ----------------
__device__ __forceinline__ float mlp_rho(float j,
    const float* sW1, const float* sB1, const float* sW2,
    const float* sB2, const float* sW3, float b3v) {
    float h1[NODES];
#pragma unroll
    for (int k = 0; k < NODES; ++k)
        h1[k] = fmaxf(fmaf(j, sW1[k], sB1[k]), 0.0f);
    float rho = b3v;
    for (int nt = 0; nt < NODES; nt += 8) {
        float acc[8];
#pragma unroll
        for (int q = 0; q < 8; ++q) acc[q] = sB2[nt + q];
#pragma unroll
        for (int k = 0; k < NODES; ++k) {
            float a = h1[k];
#pragma unroll
            for (int q = 0; q < 8; ++q)
                acc[q] = fmaf(a, sW2[k * NODES + nt + q], acc[q]);
        }
#pragma unroll
        for (int q = 0; q < 8; ++q)
            rho = fmaf(fmaxf(acc[q], 0.0f), sW3[nt + q], rho);
    }
    return rho;
}

// ---------------- kernel 1: build rho(j) table of {value, delta} ----------------
__global__ __launch_bounds__(256) void build_table(
    const float* __restrict__ W1, const float* __restrict__ b1,
    const float* __restrict__ W2, const float* __restrict__ b2,
    const float* __restrict__ W3, const float* __restrict__ b3,
    float2* __restrict__ tbl) {
    __shared__ float sW2[NODES * NODES];
    __shared__ float sW1[NODES], sB1[NODES], sB2[NODES], sW3[NODES];
    __shared__ float sB3;
    for (int i = threadIdx.x; i < NODES * NODES; i += 256) sW2[i] = W2[i];
    if (threadIdx.x < NODES) {
        sW1[threadIdx.x] = W1[threadIdx.x];
        sB1[threadIdx.x] = b1[threadIdx.x];
        sB2[threadIdx.x] = b2[threadIdx.x];
        sW3[threadIdx.x] = W3[threadIdx.x];
    }
    if (threadIdx.x == 0) sB3 = b3[0];
    __syncthreads();

    int idx = blockIdx.x * 256 + threadIdx.x;
    if (idx >= TBL_N) return;
    const float h = JMAX / (float)TBL_N;
    float j0 = h * (float)idx;
    float v0 = mlp_rho(j0,       sW1, sB1, sW2, sB2, sW3, sB3);
    float v1 = mlp_rho(j0 + h,   sW1, sB1, sW2, sB2, sW3, sB3);
    tbl[idx] = make_float2(v0, v1 - v0);
}

// ---------------- kernel 2: per-lane sequential simulation ----------------
__global__ __launch_bounds__(64) void simulate(
    const float* __restrict__ Cv, const float* __restrict__ K,
    const float* __restrict__ jmin, const float2* __restrict__ tbl,
    float* __restrict__ out) {
    __shared__ float2 stbl[TBL_N];   // 64 KB
    {
        const float4* src = (const float4*)tbl;
        float4* dst = (float4*)stbl;
        for (int i = threadIdx.x; i < TBL_N / 2; i += 64)
            dst[i] = src[i];
    }
    __syncthreads();

    const int b = blockIdx.x * 64 + threadIdx.x;
    const float cv = Cv[b];
    const float kk = K[b];
    const float jm = jmin[b];

    const float Qmin = 3.3068376f * powf(kk, 1.3333334f);

    const float DT_ = 0.1f, RF0 = 50.0f;
    const float cvDT = cv * DT_;
    const float invh = (float)TBL_N / JMAX;

    float* __restrict__ tout  = out + (size_t)b * NT;
    float* __restrict__ rout  = out + (size_t)BATCH * NT + (size_t)b * NT;
    float* __restrict__ cout_ = out + 2 * (size_t)BATCH * NT + (size_t)b * NT;
    float* __restrict__ timo  = out + 3 * (size_t)BATCH * NT + (size_t)b * NT;

    tout[0]  = 0.0f;
    rout[0]  = RF0;
    cout_[0] = 1e-3f;
    timo[0]  = 0.0f;

    float res = RF0, thk = 0.0f, Q = 0.0f;

    // prefetch state for steps i and i+1 (value/delta pair + fractional pos)
    // initial jcur values are exact while res==50: jcur_i = 0.00175*(i+1)
    float2 pv0, pv1;
    float  pfr0, pfr1;
    {
        float x = 0.00175f * invh;
        x = fminf(fmaxf(x, 0.0f), (float)(TBL_N - 1) - 0.001f);
        int i0 = (int)x; pfr0 = x - (float)i0; pv0 = stbl[i0];
        x = 0.00350f * invh;
        x = fminf(fmaxf(x, 0.0f), (float)(TBL_N - 1) - 0.001f);
        i0 = (int)x; pfr1 = x - (float)i0; pv1 = stbl[i0];
    }
    float jprev = 0.0f;  // jcur at "i-1" (extrapolation is exact pre-crossing)

#pragma unroll 4
    for (int i = 0; i < NT - 1; ++i) {
        float BC   = DT_ * (float)(i + 1);                 // VR = 1
        float den  = fmaf(0.14f, res, 1.0f);
        float jcur = (0.14f * BC) * __builtin_amdgcn_rcpf(den);
        float Qn   = fmaf(jcur, DT_, Q);

        // issue prefetch for step i+2: jpred = 3*jcur - 2*jprev
        float jpred = fmaf(2.0f, jcur - jprev, jcur);
        jprev = jcur;
        float xp = jpred * invh;
        xp = fminf(fmaxf(xp, 0.0f), (float)(TBL_N - 1) - 0.001f);
        int ip = (int)xp;
        float pfrn = xp - (float)ip;
        float2 pvn = stbl[ip];

        // rho for the CURRENT step from the prefetch issued 2 iterations ago
        float rho   = fmaf(pfr0, pv0.y, pv0.x);
        float rcDT  = rho * cvDT;          // off the jcur-dependent chain

        // rotate prefetch pipeline
        pv0 = pv1; pfr0 = pfr1;
        pv1 = pvn; pfr1 = pfrn;

        float d1    = jcur - jm;
        float thk_c = fmaf(d1, cvDT, thk);
        float thk_l = fmaxf(thk_c, 0.0f);       // _limit(.., 0)
        float res_c = fmaf(d1, rcDT, res);
        float res_l = fmaxf(res_c, RF0);        // _limit(.., 50)

        bool upd = Qn > Qmin;                   // _tradeoff step
        thk = upd ? thk_l : thk;
        res = upd ? res_l : res;
        Q   = Qn;

        int o = i + 1;
        tout[o]  = thk;
        rout[o]  = res;
        cout_[o] = jcur;
        timo[o]  = BC;
    }
}

extern "C" void kernel_launch(void* const* d_in, const int* in_sizes, int n_in,
                              void* d_out, int out_size, void* d_ws, size_t ws_size,
                              hipStream_t stream) {
    const float* Cv   = (const float*)d_in[0];
    const float* K    = (const float*)d_in[1];
    const float* jmin = (const float*)d_in[2];
    const float* W1   = (const float*)d_in[3];
    const float* b1   = (const float*)d_in[4];
    const float* W2   = (const float*)d_in[5];
    const float* b2   = (const float*)d_in[6];
    const float* W3   = (const float*)d_in[7];
    const float* b3   = (const float*)d_in[8];
    float* out = (float*)d_out;
    float2* tbl = (float2*)d_ws;   // TBL_N float2 = 64 KB of scratch

    build_table<<<TBL_N / 256, 256, 0, stream>>>(W1, b1, W2, b2, W3, b3, tbl);
    simulate<<<BATCH / 64, 64, 0, stream>>>(Cv, K, jmin, tbl, out);
}

// Round 3
// 235.956 us; speedup vs baseline: 2.3315x; 1.0432x over previous
//
#include <hip/hip_runtime.h>

#define NT      2000
#define BATCH   4096
#define NODES   64
#define TBL_N   8192
#define JMAX    3.6f
#define CH      16
#define LROW    20              // padded words per chain row in staging
#define SECW    (64 * LROW)     // words per stream section (1280)

// ---------------- MLP evaluation helper (build phase only) ----------------
__device__ __forceinline__ float mlp_rho(float j,
    const float* sW1, const float* sB1, const float* sW2,
    const float* sB2, const float* sW3, float b3v) {
    float h1[NODES];
#pragma unroll
    for (int k = 0; k < NODES; ++k)
        h1[k] = fmaxf(fmaf(j, sW1[k], sB1[k]), 0.0f);
    float rho = b3v;
    for (int nt = 0; nt < NODES; nt += 8) {
        float acc[8];
#pragma unroll
        for (int q = 0; q < 8; ++q) acc[q] = sB2[nt + q];
#pragma unroll
        for (int k = 0; k < NODES; ++k) {
            float a = h1[k];
#pragma unroll
            for (int q = 0; q < 8; ++q)
                acc[q] = fmaf(a, sW2[k * NODES + nt + q], acc[q]);
        }
#pragma unroll
        for (int q = 0; q < 8; ++q)
            rho = fmaf(fmaxf(acc[q], 0.0f), sW3[nt + q], rho);
    }
    return rho;
}

// ---------------- kernel 1: build rho(j) table ----------------
__global__ __launch_bounds__(256) void build_table(
    const float* __restrict__ W1, const float* __restrict__ b1,
    const float* __restrict__ W2, const float* __restrict__ b2,
    const float* __restrict__ W3, const float* __restrict__ b3,
    float* __restrict__ tbl) {
    __shared__ float sW2[NODES * NODES];
    __shared__ float sW1[NODES], sB1[NODES], sB2[NODES], sW3[NODES];
    __shared__ float sB3;
    for (int i = threadIdx.x; i < NODES * NODES; i += 256) sW2[i] = W2[i];
    if (threadIdx.x < NODES) {
        sW1[threadIdx.x] = W1[threadIdx.x];
        sB1[threadIdx.x] = b1[threadIdx.x];
        sB2[threadIdx.x] = b2[threadIdx.x];
        sW3[threadIdx.x] = W3[threadIdx.x];
    }
    if (threadIdx.x == 0) sB3 = b3[0];
    __syncthreads();

    int idx = blockIdx.x * 256 + threadIdx.x;
    if (idx >= TBL_N) return;
    const float h = JMAX / (float)TBL_N;
    tbl[idx] = mlp_rho(h * (float)idx, sW1, sB1, sW2, sB2, sW3, sB3);
}

// ---------------- kernel 2: per-lane sequential simulation ----------------
__global__ __launch_bounds__(64, 1) void simulate(
    const float* __restrict__ Cv, const float* __restrict__ K,
    const float* __restrict__ jmin, const float* __restrict__ tbl,
    float* __restrict__ out) {
    __shared__ float stbl[TBL_N];          // 32 KB
    __shared__ float sbuf[3 * SECW];       // 15 KB staging (thk,res,jcur)

    const int l = threadIdx.x;
    for (int i = l; i < TBL_N / 4; i += 64)
        reinterpret_cast<float4*>(stbl)[i] =
            reinterpret_cast<const float4*>(tbl)[i];
    __syncthreads();

    const int b0 = blockIdx.x * 64;
    const int b = b0 + l;
    const float cv = Cv[b];
    const float kk = K[b];
    const float jm = jmin[b];
    const float Qmin = 3.3068376f * powf(kk, 1.3333334f);
    const float cvDT = cv * 0.1f;
    const float invh = (float)TBL_N / JMAX;

    // staging addresses
    float* __restrict__ wbase = &sbuf[l * LROW];              // per-step writes
    const int r = l >> 2, q = l & 3;
    const float* __restrict__ rbase = &sbuf[r * LROW + 4 * q]; // flush reads

    float* __restrict__ oT  = out;
    float* __restrict__ oR  = out + (size_t)BATCH * NT;
    float* __restrict__ oC  = out + 2 * (size_t)BATCH * NT;
    float* __restrict__ oTm = out + 3 * (size_t)BATCH * NT;
    const size_t wo = (size_t)(b0 + r) * NT + 4 * q;  // + m*16*NT + 16*c

    float res = 50.0f, thk = 0.0f, Q = 0.0f, jprev = 0.0f;

    // prefetch pipeline (rho pair+frac) for o=1, o=2 — res==50 exactly there
    float t00, t10, f0, t01, t11, f1;
    {
        float x = 0.00175f * invh;
        int ip = (int)x; f0 = x - (float)ip; t00 = stbl[ip]; t10 = stbl[ip + 1];
        x = 0.00350f * invh;
        ip = (int)x; f1 = x - (float)ip; t01 = stbl[ip]; t11 = stbl[ip + 1];
    }

    // o = 0 initial values into slot 0
    wbase[0 * SECW + 0] = 0.0f;
    wbase[1 * SECW + 0] = 50.0f;
    wbase[2 * SECW + 0] = 1e-3f;

    auto step = [&](int o, int slot) {
        float BC   = 0.1f * (float)o;                       // VR*DT*(i+1)
        float den  = fmaf(0.14f, res, 1.0f);
        float jcur = (0.14f * BC) * __builtin_amdgcn_rcpf(den);
        float Qn   = fmaf(jcur, 0.1f, Q);

        // prefetch rho pair for step o+2
        float jpred = fmaf(2.0f, jcur - jprev, jcur);
        jprev = jcur;
        float xp = fminf(fmaxf(jpred * invh, 0.0f), (float)(TBL_N - 2));
        int ip = (int)xp;
        float fn = xp - (float)ip;
        float a0 = stbl[ip], a1 = stbl[ip + 1];

        // rho for current step (prefetched 2 iterations ago)
        float rho  = fmaf(f0, t10 - t00, t00);
        float rcDT = rho * cvDT;
        t00 = t01; t10 = t11; f0 = f1;
        t01 = a0;  t11 = a1;  f1 = fn;

        float d1    = jcur - jm;
        float thk_l = fmaxf(fmaf(d1, cvDT, thk), 0.0f);   // _limit(..,0)
        float res_l = fmaxf(fmaf(d1, rcDT, res), 50.0f);  // _limit(..,50)
        bool upd = Qn > Qmin;                             // _tradeoff gate
        thk = upd ? thk_l : thk;
        res = upd ? res_l : res;
        Q = Qn;

        wbase[0 * SECW + slot] = thk;
        wbase[1 * SECW + slot] = res;
        wbase[2 * SECW + slot] = jcur;
    };

    auto flush = [&](int c) {
        __syncthreads();
        const size_t cb = (size_t)(16 * c);
        const int tt = 16 * c + 4 * q;
#pragma unroll
        for (int m = 0; m < 4; ++m) {
            float4 vT = *reinterpret_cast<const float4*>(rbase + 0 * SECW + m * 16 * LROW);
            float4 vR = *reinterpret_cast<const float4*>(rbase + 1 * SECW + m * 16 * LROW);
            float4 vC = *reinterpret_cast<const float4*>(rbase + 2 * SECW + m * 16 * LROW);
            size_t off = wo + (size_t)m * 16 * NT + cb;
            *reinterpret_cast<float4*>(oT + off) = vT;
            *reinterpret_cast<float4*>(oR + off) = vR;
            *reinterpret_cast<float4*>(oC + off) = vC;
            *reinterpret_cast<float4*>(oTm + off) = make_float4(
                0.1f * (float)tt, 0.1f * (float)(tt + 1),
                0.1f * (float)(tt + 2), 0.1f * (float)(tt + 3));
        }
        __syncthreads();
    };

    // chunk 0: o = 1..15 (slot 0 holds initial values)
#pragma unroll
    for (int s = 1; s < CH; ++s) step(s, s);
    flush(0);

    for (int c = 1; c < NT / CH; ++c) {
#pragma unroll
        for (int s = 0; s < CH; ++s) step(16 * c + s, s);
        flush(c);
    }
}

extern "C" void kernel_launch(void* const* d_in, const int* in_sizes, int n_in,
                              void* d_out, int out_size, void* d_ws, size_t ws_size,
                              hipStream_t stream) {
    const float* Cv   = (const float*)d_in[0];
    const float* K    = (const float*)d_in[1];
    const float* jmin = (const float*)d_in[2];
    const float* W1   = (const float*)d_in[3];
    const float* b1   = (const float*)d_in[4];
    const float* W2   = (const float*)d_in[5];
    const float* b2   = (const float*)d_in[6];
    const float* W3   = (const float*)d_in[7];
    const float* b3   = (const float*)d_in[8];
    float* out = (float*)d_out;
    float* tbl = (float*)d_ws;   // TBL_N floats = 32 KB scratch

    build_table<<<TBL_N / 256, 256, 0, stream>>>(W1, b1, W2, b2, W3, b3, tbl);
    simulate<<<BATCH / 64, 64, 0, stream>>>(Cv, K, jmin, tbl, out);
}